// Round 3
// baseline (9109.879 us; speedup 1.0000x reference)
//
#include <hip/hip_runtime.h>

// ============================================================================
// Compile-time replication of the reference's Wigner-3j / tensor-product
// structure (Racah formula + e3nn real<->complex change of basis).
// ============================================================================

constexpr double cfact(int n){ double r = 1.0; for (int i = 2; i <= n; ++i) r *= (double)i; return r; }

constexpr double csqrt(double x){
  if (x <= 0.0) return 0.0;
  double g = x > 1.0 ? x : 1.0;
  for (int i = 0; i < 100; ++i) g = 0.5*(g + x/g);
  return g;
}

struct CD { double re, im; };

constexpr double su2_cg(int j1,int j2,int j3,int m1,int m2){
  int m3 = m1 + m2;
  if (m3 < -j3 || m3 > j3) return 0.0;
  double p1 = (2.0*j3+1.0)*cfact(j1+j2-j3)*cfact(j1-j2+j3)*cfact(-j1+j2+j3)/cfact(j1+j2+j3+1);
  double p2 = cfact(j1+m1)*cfact(j1-m1)*cfact(j2+m2)*cfact(j2-m2)*cfact(j3+m3)*cfact(j3-m3);
  double pref = csqrt(p1*p2);
  int k0 = 0;
  if (j2-j3-m1 > k0) k0 = j2-j3-m1;
  if (j1+m2-j3 > k0) k0 = j1+m2-j3;
  int k1 = j1+j2-j3;
  if (j1-m1 < k1) k1 = j1-m1;
  if (j2+m2 < k1) k1 = j2+m2;
  double s = 0.0;
  for (int k = k0; k <= k1; ++k){
    double t = 1.0/(cfact(k)*cfact(j1+j2-j3-k)*cfact(j1-m1-k)*cfact(j2+m2-k)
                    *cfact(j3-j2+m1+k)*cfact(j3-j1-m2+k));
    s += (k & 1) ? -t : t;
  }
  return pref*s;
}

struct QRow { int n; int col[2]; CD q[2]; };
constexpr QRow qrow(int l, int r){
  QRow R{};
  constexpr double s2 = 0.70710678118654752440;
  int m = r - l;
  if (m < 0){
    R.n = 2;
    R.col[0] = l - m; R.q[0] = CD{s2, 0.0};
    R.col[1] = l + m; R.q[1] = CD{0.0, -s2};
  } else if (m == 0){
    R.n = 1; R.col[0] = l; R.q[0] = CD{1.0, 0.0};
  } else {
    double sg = (m & 1) ? -1.0 : 1.0;
    R.n = 2;
    R.col[0] = l + m; R.q[0] = CD{sg*s2, 0.0};
    R.col[1] = l - m; R.q[1] = CD{0.0, sg*s2};
  }
  int ph = l & 3;   // multiply by (-i)^l
  for (int t = 0; t < R.n; ++t){
    double a = R.q[t].re, b = R.q[t].im;
    if      (ph == 1) R.q[t] = CD{ b, -a};
    else if (ph == 2) R.q[t] = CD{-a, -b};
    else if (ph == 3) R.q[t] = CD{-b,  a};
  }
  return R;
}

constexpr int MAXNZ = 160;
struct W3NZ { int n; int ijk[MAXNZ]; float v[MAXNZ]; };

constexpr W3NZ build_w3(int l1,int l2,int l3){
  double re[7][7][7]{};
  int d1 = 2*l1+1, d2 = 2*l2+1, d3 = 2*l3+1;
  for (int i = 0; i < d1; ++i) for (int k = 0; k < d2; ++k){
    int m1 = i - l1, m2 = k - l2, m3 = m1 + m2;
    if (m3 < -l3 || m3 > l3) continue;
    int n = m3 + l3;
    double cg = su2_cg(l1,l2,l3,m1,m2);
    if (cg == 0.0) continue;
    QRow q1 = qrow(l1,i), q2 = qrow(l2,k), q3 = qrow(l3,n);
    for (int a = 0; a < q1.n; ++a) for (int b = 0; b < q2.n; ++b) for (int c = 0; c < q3.n; ++c){
      CD A = q1.q[a], B = q2.q[b], C = q3.q[c];
      C.im = -C.im;
      CD AB{A.re*B.re - A.im*B.im, A.re*B.im + A.im*B.re};
      double tre = AB.re*C.re - AB.im*C.im;
      re[q1.col[a]][q2.col[b]][q3.col[c]] += tre*cg;
    }
  }
  double nrm = 0.0;
  for (int i = 0; i < d1; ++i) for (int j = 0; j < d2; ++j) for (int k = 0; k < d3; ++k)
    nrm += re[i][j][k]*re[i][j][k];
  nrm = csqrt(nrm);
  W3NZ R{};
  for (int i = 0; i < d1; ++i) for (int j = 0; j < d2; ++j) for (int k = 0; k < d3; ++k){
    double val = re[i][j][k]/nrm;
    if (val > 1e-9 || val < -1e-9){
      R.ijk[R.n] = i | (j << 3) | (k << 6);
      R.v[R.n]   = (float)val;
      R.n++;
    }
  }
  return R;
}

struct C3 { int l1,l2,l3; };
constexpr C3 combo_at(int cid){
  int c = 0;
  for (int a = 0; a <= 3; ++a) for (int b = 0; b <= 3; ++b){
    int lmin = a > b ? a-b : b-a;
    int lmax = a+b > 3 ? 3 : a+b;
    for (int lo = lmin; lo <= lmax; ++lo){ if (c == cid) return C3{a,b,lo}; ++c; }
  }
  return C3{0,0,0};
}
constexpr int cid_of(int l1,int l2,int l3){
  int c = 0;
  for (int a = 0; a <= 3; ++a) for (int b = 0; b <= 3; ++b){
    int lmin = a > b ? a-b : b-a;
    int lmax = a+b > 3 ? 3 : a+b;
    for (int lo = lmin; lo <= lmax; ++lo){ if (a==l1 && b==l2 && lo==l3) return c; ++c; }
  }
  return -1;
}

template<int C> struct W3Tab {
  static constexpr W3NZ v = build_w3(combo_at(C).l1, combo_at(C).l2, combo_at(C).l3);
};

// ----------------------------------------------------------------------------
// Tensor-product path tables. scale folds sqrt((2lo+1)/fan) * 0.25 (neighbor
// normalization of the input node features).
// ----------------------------------------------------------------------------
struct Irr { int mul, l, p; };
constexpr Irr IRR_SH_A[4]  = {{1,0,1},{1,1,-1},{1,2,1},{1,3,-1}};
constexpr Irr IRR_MID_A[8] = {{5,0,-1},{5,0,1},{5,1,-1},{5,1,1},{5,2,-1},{5,2,1},{5,3,-1},{5,3,1}};
constexpr Irr IRR_OUT_A[1] = {{64,0,1}};

struct PathT { int o1,m1,l1,o2,l2,oo,mo,lo,ioi,wof,cid; float scale; };
struct TPD   { int np; int d1tot, d2tot, dotot, wtot; PathT p[68]; };

constexpr TPD build_tp(const Irr* I1, int n1, const Irr* I2, int n2, const Irr* IO, int no){
  TPD T{};
  int o1s[8]{}, o2s[8]{}, oos[8]{};
  { int off=0; for (int i=0;i<n1;++i){ o1s[i]=off; off += I1[i].mul*(2*I1[i].l+1); } T.d1tot=off; }
  { int off=0; for (int i=0;i<n2;++i){ o2s[i]=off; off += I2[i].mul*(2*I2[i].l+1); } T.d2tot=off; }
  { int off=0; for (int i=0;i<no;++i){ oos[i]=off; off += IO[i].mul*(2*IO[i].l+1); } T.dotot=off; }
  int wof = 0;
  for (int i1=0;i1<n1;++i1) for (int i2=0;i2<n2;++i2) for (int io=0;io<no;++io){
    int L1=I1[i1].l, L2=I2[i2].l, LO=IO[io].l;
    int dl = L1>L2 ? L1-L2 : L2-L1;
    if (IO[io].p == I1[i1].p*I2[i2].p && dl <= LO && LO <= L1+L2){
      PathT& P = T.p[T.np];
      P.o1=o1s[i1]; P.m1=I1[i1].mul; P.l1=L1;
      P.o2=o2s[i2]; P.l2=L2;
      P.oo=oos[io]; P.mo=IO[io].mul; P.lo=LO; P.ioi=io;
      P.wof=wof; P.cid=cid_of(L1,L2,LO);
      wof += I1[i1].mul * I2[i2].mul * IO[io].mul;
      T.np++;
    }
  }
  T.wtot = wof;
  for (int p = 0; p < T.np; ++p){
    int fan = 0;
    for (int q = 0; q < T.np; ++q) if (T.p[q].ioi == T.p[p].ioi) fan += T.p[q].m1;
    T.p[p].scale = (float)(csqrt((2.0*T.p[p].lo+1.0)/(double)fan) * 0.25);
  }
  return T;
}

template<int ID> struct TPSel;
template<> struct TPSel<0>{ static constexpr TPD v = build_tp(IRR_SH_A,4,  IRR_SH_A,4, IRR_MID_A,8); };
template<> struct TPSel<1>{ static constexpr TPD v = build_tp(IRR_MID_A,8, IRR_SH_A,4, IRR_MID_A,8); };
template<> struct TPSel<2>{ static constexpr TPD v = build_tp(IRR_MID_A,8, IRR_SH_A,4, IRR_OUT_A,1); };

static_assert(TPSel<0>::v.np == 34 && TPSel<0>::v.wtot == 170,  "TP_IN structure mismatch");
static_assert(TPSel<1>::v.np == 68 && TPSel<1>::v.wtot == 1700, "TP_LAYER structure mismatch");
static_assert(TPSel<2>::v.np == 4  && TPSel<2>::v.wtot == 1280, "TP_OUT structure mismatch");
static_assert(TPSel<0>::v.d1tot == 16 && TPSel<0>::v.dotot == 160, "dims");
static_assert(TPSel<1>::v.d1tot == 160 && TPSel<1>::v.dotot == 160, "dims");
static_assert(TPSel<2>::v.d1tot == 160 && TPSel<2>::v.dotot == 64, "dims");

constexpr int path_count_into(const TPD& T, int io){
  int c = 0; for (int q = 0; q < T.np; ++q) if (T.p[q].ioi == io) ++c; return c;
}
constexpr int out_off_of(const TPD& T, int io){
  for (int q = 0; q < T.np; ++q) if (T.p[q].ioi == io) return T.p[q].oo; return 0;
}

// Compile-time for-loop
template<int V> struct IC { static constexpr int value = V; };
template<int I, int N, class F>
__device__ __forceinline__ void sfor(F&& f){
  if constexpr (N - I == 1){ f(IC<I>{}); }
  else if constexpr (N - I > 1){
    constexpr int M = I + (N - I)/2;
    sfor<I, M>(f);
    sfor<M, N>(f);
  }
}

// ============================================================================
// Kernels
// ============================================================================

__device__ __forceinline__ void sh16(float x, float y, float z, float* b){
  const float s3 = 1.7320508075688772f, s5 = 2.2360679774997896f, s7 = 2.6457513110645907f;
  const float c30 = 0.9128709291752769f;   // sqrt(5/6)
  const float c32 = 0.6123724356957945f;   // sqrt(3/8)
  float y2 = y*y, x2z2 = x*x + z*z;
  float sh20 = s3*x*z, sh21 = s3*x*y, sh22 = y2 - 0.5f*x2z2, sh23 = s3*y*z, sh24 = 0.5f*s3*(z*z - x*x);
  float sh30 = c30*(sh20*z + sh24*x);
  float sh31 = s5*sh20*y;
  float sh32 = c32*(4.0f*y2 - x2z2)*x;
  float sh33 = 0.5f*y*(2.0f*y2 - 3.0f*x2z2);
  float sh34 = c32*z*(4.0f*y2 - x2z2);
  float sh35 = s5*sh24*y;
  float sh36 = c30*(sh24*z - sh20*x);
  b[0]=1.0f; b[1]=s3*x; b[2]=s3*y; b[3]=s3*z;
  b[4]=s5*sh20; b[5]=s5*sh21; b[6]=s5*sh22; b[7]=s5*sh23; b[8]=s5*sh24;
  b[9]=s7*sh30; b[10]=s7*sh31; b[11]=s7*sh32; b[12]=s7*sh33; b[13]=s7*sh34; b[14]=s7*sh35; b[15]=s7*sh36;
}

// --- CSR build --------------------------------------------------------------

__global__ void __launch_bounds__(256) k_hist(const int* __restrict__ dst,
    int* __restrict__ deg, int E){
  int e = blockIdx.x*256 + threadIdx.x;
  if (e < E) atomicAdd(&deg[dst[e]], 1);
}

// single block, 256 threads: exclusive scan of deg[0..N) -> row_start[0..N]
__global__ void __launch_bounds__(256) k_scan(const int* __restrict__ deg,
    int* __restrict__ row_start, int* __restrict__ cursor, int N){
  __shared__ int part[256];
  int t = threadIdx.x;
  int M = N + 1;
  int CH = (M + 255) / 256;
  int base = t * CH;
  int s = 0;
  for (int k = 0; k < CH; ++k){
    int idx = base + k;
    if (idx < N) s += deg[idx];
  }
  part[t] = s;
  __syncthreads();
  if (t == 0){
    int run = 0;
    for (int i = 0; i < 256; ++i){ int v = part[i]; part[i] = run; run += v; }
  }
  __syncthreads();
  int run = part[t];
  for (int k = 0; k < CH; ++k){
    int idx = base + k;
    if (idx < M){
      row_start[idx] = run;
      cursor[idx] = run;
      if (idx < N) run += deg[idx];
    }
  }
}

// scatter edges into CSR order; precompute spherical harmonics per edge
__global__ void __launch_bounds__(256) k_fill(const int* __restrict__ src,
    const int* __restrict__ dst, const float* __restrict__ evec,
    int* __restrict__ cursor, int* __restrict__ csr_src, float* __restrict__ csr_sh, int E){
  int e = blockIdx.x*256 + threadIdx.x;
  if (e >= E) return;
  int d = dst[e];
  int pos = atomicAdd(&cursor[d], 1);
  csr_src[pos] = src[e];
  float b[16];
  sh16(evec[3*(size_t)e], evec[3*(size_t)e+1], evec[3*(size_t)e+2], b);
  float4* o = (float4*)(csr_sh + (size_t)pos*16);
  o[0] = make_float4(b[0],b[1],b[2],b[3]);
  o[1] = make_float4(b[4],b[5],b[6],b[7]);
  o[2] = make_float4(b[8],b[9],b[10],b[11]);
  o[3] = make_float4(b[12],b[13],b[14],b[15]);
}

// nodeA[n][d] = sum of csr_sh rows of node n (raw, un-normalized)
__global__ void __launch_bounds__(256) k_nodeA(const float* __restrict__ csr_sh,
    const int* __restrict__ row_start, float* __restrict__ nodeA, int N){
  int gid = blockIdx.x*256 + threadIdx.x;
  if (gid >= N*16) return;
  int n = gid >> 4, d = gid & 15;
  int rs = row_start[n], re = row_start[n+1];
  float s = 0.f;
  for (int j = rs; j < re; ++j) s += csr_sh[(size_t)j*16 + d];
  nodeA[gid] = s;
}

// --- fused TP + per-node reduce (no atomics) --------------------------------
// block = (64 nodes) x (8 waves). Wave y owns output-irrep block y (TP0/TP1)
// or output columns [8y, 8y+8) (TP2). Lane = node. Single coalesced store.

template<int TPID>
__global__ void __launch_bounds__(512, 2) k_tp_csr(
    const float* __restrict__ nin, const float* __restrict__ csr_sh,
    const int* __restrict__ csr_src, const int* __restrict__ row_start,
    const float* __restrict__ w, float* __restrict__ nout, int N)
{
  constexpr int D1 = TPSel<TPID>::v.d1tot;
  constexpr int DO = TPSel<TPID>::v.dotot;
  int n  = blockIdx.x*64 + (int)threadIdx.x;
  int ty = __builtin_amdgcn_readfirstlane((int)threadIdx.y);
  bool valid = n < N;
  int rs = valid ? row_start[n]   : 0;
  int re = valid ? row_start[n+1] : 0;

  if constexpr (TPID != 2){
    sfor<0, 8>([&](auto IOC){
      constexpr int IO = decltype(IOC)::value;
      constexpr Irr OI = IRR_MID_A[IO];
      constexpr int dd  = 2*OI.l + 1;
      constexpr int ACC = OI.mul * dd;
      if (ty == IO){
        float acc[ACC];
        #pragma unroll
        for (int i = 0; i < ACC; ++i) acc[i] = 0.0f;

        for (int j = rs; j < re; ++j){
          int s = csr_src[j];
          float b[16];
          { const float4* sp = (const float4*)(csr_sh + (size_t)j*16);
            float4 q0=sp[0], q1=sp[1], q2=sp[2], q3=sp[3];
            b[0]=q0.x; b[1]=q0.y; b[2]=q0.z;  b[3]=q0.w;
            b[4]=q1.x; b[5]=q1.y; b[6]=q1.z;  b[7]=q1.w;
            b[8]=q2.x; b[9]=q2.y; b[10]=q2.z; b[11]=q2.w;
            b[12]=q3.x;b[13]=q3.y;b[14]=q3.z; b[15]=q3.w; }
          const float* __restrict__ arow = nin + (size_t)s*D1;
          float a16[16];
          if constexpr (D1 == 16){
            const float4* ap = (const float4*)arow;
            float4 q0=ap[0], q1=ap[1], q2=ap[2], q3=ap[3];
            a16[0]=q0.x; a16[1]=q0.y; a16[2]=q0.z;  a16[3]=q0.w;
            a16[4]=q1.x; a16[5]=q1.y; a16[6]=q1.z;  a16[7]=q1.w;
            a16[8]=q2.x; a16[9]=q2.y; a16[10]=q2.z; a16[11]=q2.w;
            a16[12]=q3.x;a16[13]=q3.y;a16[14]=q3.z; a16[15]=q3.w;
          }

          sfor<0, TPSel<TPID>::v.np>([&](auto PC){
            constexpr PathT P = TPSel<TPID>::v.p[decltype(PC)::value];
            if constexpr (P.ioi == IO){
              constexpr int d1 = 2*P.l1 + 1;
              float av[P.m1*d1];
              #pragma unroll
              for (int i = 0; i < P.m1*d1; ++i){
                if constexpr (D1 == 16) av[i] = a16[P.o1 + i];
                else                    av[i] = arow[P.o1 + i];
              }
              float t[P.m1*dd];
              #pragma unroll
              for (int i = 0; i < P.m1*dd; ++i) t[i] = 0.0f;
              sfor<0, W3Tab<P.cid>::v.n>([&](auto NI){
                constexpr int ni  = decltype(NI)::value;
                constexpr int ijk = W3Tab<P.cid>::v.ijk[ni];
                constexpr int ii = ijk & 7, jj = (ijk >> 3) & 7, kk = ijk >> 6;
                constexpr float v = W3Tab<P.cid>::v.v[ni];
                float bv = b[P.o2 + jj] * v;
                #pragma unroll
                for (int u = 0; u < P.m1; ++u) t[u*dd + kk] += av[u*d1 + ii]*bv;
              });
              #pragma unroll
              for (int u = 0; u < P.m1; ++u){
                #pragma unroll
                for (int wj = 0; wj < OI.mul; ++wj){
                  float wv = w[P.wof + u*OI.mul + wj] * P.scale;
                  #pragma unroll
                  for (int k = 0; k < dd; ++k) acc[wj*dd + k] += wv * t[u*dd + k];
                }
              }
            }
          });
        }

        if (valid){
          constexpr int OB = out_off_of(TPSel<TPID>::v, IO);
          #pragma unroll
          for (int i = 0; i < ACC; ++i) nout[(size_t)n*DO + OB + i] = acc[i];
        }
      }
    });
  } else {
    // TP_OUT: 4 paths (l,l,0); wave y owns output columns [8y, 8y+8)
    int wj0 = ty * 8;
    float acc[8];
    #pragma unroll
    for (int i = 0; i < 8; ++i) acc[i] = 0.0f;
    for (int j = rs; j < re; ++j){
      float b[16];
      { const float4* sp = (const float4*)(csr_sh + (size_t)j*16);
        float4 q0=sp[0], q1=sp[1], q2=sp[2], q3=sp[3];
        b[0]=q0.x; b[1]=q0.y; b[2]=q0.z;  b[3]=q0.w;
        b[4]=q1.x; b[5]=q1.y; b[6]=q1.z;  b[7]=q1.w;
        b[8]=q2.x; b[9]=q2.y; b[10]=q2.z; b[11]=q2.w;
        b[12]=q3.x;b[13]=q3.y;b[14]=q3.z; b[15]=q3.w; }
      const float* __restrict__ arow = nin + (size_t)csr_src[j]*D1;
      sfor<0, 4>([&](auto PC){
        constexpr PathT P = TPSel<2>::v.p[decltype(PC)::value];
        constexpr int d1 = 2*P.l1 + 1;
        float t[5];
        #pragma unroll
        for (int u = 0; u < 5; ++u) t[u] = 0.0f;
        sfor<0, W3Tab<P.cid>::v.n>([&](auto NI){
          constexpr int ni  = decltype(NI)::value;
          constexpr int ijk = W3Tab<P.cid>::v.ijk[ni];
          constexpr int ii = ijk & 7, jj = (ijk >> 3) & 7;
          constexpr float v = W3Tab<P.cid>::v.v[ni];
          float bv = b[P.o2 + jj] * v;
          #pragma unroll
          for (int u = 0; u < 5; ++u) t[u] += arow[P.o1 + u*d1 + ii]*bv;
        });
        #pragma unroll
        for (int u = 0; u < 5; ++u){
          float ts = t[u] * P.scale;
          #pragma unroll
          for (int q = 0; q < 8; ++q) acc[q] += w[P.wof + u*64 + wj0 + q] * ts;
        }
      });
    }
    if (valid){
      #pragma unroll
      for (int q = 0; q < 8; ++q) nout[(size_t)n*64 + wj0 + q] = acc[q];
    }
  }
}

// --- final per-graph reduce (batch is sorted -> binary search, no atomics) --
__device__ __forceinline__ int lbound(const int* __restrict__ a, int n, int key){
  int lo = 0, hi = n;
  while (lo < hi){ int m = (lo + hi) >> 1; if (a[m] < key) lo = m + 1; else hi = m; }
  return lo;
}

__global__ void __launch_bounds__(64) k_graph(const float* __restrict__ nodeD,
    const int* __restrict__ batch, float* __restrict__ out, int N){
  int g = blockIdx.x, f = threadIdx.x;
  int lo = lbound(batch, N, g), hi = lbound(batch, N, g + 1);
  float s = 0.f;
  for (int n = lo; n < hi; ++n) s += nodeD[(size_t)n*64 + f];
  out[(size_t)g*64 + f] = s * 2.5e-6f;   // 0.25 / sqrt(100) / 1e4
}

// ============================================================================
extern "C" void kernel_launch(void* const* d_in, const int* in_sizes, int n_in,
                              void* d_out, int out_size, void* d_ws, size_t ws_size,
                              hipStream_t stream){
  const int*   eidx  = (const int*)d_in[0];
  const float* evec  = (const float*)d_in[1];
  const int*   batch = (const int*)d_in[2];
  const float* w_in  = (const float*)d_in[3];
  const float* w_ly  = (const float*)d_in[4];
  const float* w_out = (const float*)d_in[5];

  const int E = in_sizes[0]/2;   // 400000
  const int N = in_sizes[2];     // 25000
  const int G = out_size/64;     // 250
  const int* src = eidx;
  const int* dstp = eidx + E;

  const int NP = (N + 1 + 3) & ~3;          // padded (N+1) for 16B alignment
  int*   deg       = (int*)d_ws;            // [NP]
  int*   row_start = deg + NP;              // [NP]
  int*   cursor    = row_start + NP;        // [NP]
  int*   csr_src   = cursor + NP;           // [E]
  float* csr_sh    = (float*)(csr_src + E); // [E,16]
  float* nodeA     = csr_sh + (size_t)E*16; // [N,16]
  float* nodeB     = nodeA + (size_t)N*16;  // [N,160]
  float* nodeC     = nodeB + (size_t)N*160; // [N,160]
  float* nodeD     = nodeC + (size_t)N*160; // [N,64]

  hipMemsetAsync(deg, 0, (size_t)NP*sizeof(int), stream);

  int nbE = (E + 255)/256;
  k_hist<<<nbE, 256, 0, stream>>>(dstp, deg, E);
  k_scan<<<1, 256, 0, stream>>>(deg, row_start, cursor, N);
  k_fill<<<nbE, 256, 0, stream>>>(src, dstp, evec, cursor, csr_src, csr_sh, E);
  k_nodeA<<<(N*16 + 255)/256, 256, 0, stream>>>(csr_sh, row_start, nodeA, N);

  dim3 blk(64, 8, 1);
  int nbN = (N + 63)/64;
  k_tp_csr<0><<<nbN, blk, 0, stream>>>(nodeA, csr_sh, csr_src, row_start, w_in,  nodeB, N);
  k_tp_csr<1><<<nbN, blk, 0, stream>>>(nodeB, csr_sh, csr_src, row_start, w_ly,  nodeC, N);
  k_tp_csr<2><<<nbN, blk, 0, stream>>>(nodeC, csr_sh, csr_src, row_start, w_out, nodeD, N);

  k_graph<<<G, 64, 0, stream>>>(nodeD, batch, (float*)d_out, N);
}

// Round 4
// 1367.834 us; speedup vs baseline: 6.6601x; 6.6601x over previous
//
#include <hip/hip_runtime.h>

// ============================================================================
// Compile-time replication of the reference's Wigner-3j / tensor-product
// structure (Racah formula + e3nn real<->complex change of basis).
// ============================================================================

constexpr double cfact(int n){ double r = 1.0; for (int i = 2; i <= n; ++i) r *= (double)i; return r; }

constexpr double csqrt(double x){
  if (x <= 0.0) return 0.0;
  double g = x > 1.0 ? x : 1.0;
  for (int i = 0; i < 100; ++i) g = 0.5*(g + x/g);
  return g;
}

struct CD { double re, im; };

constexpr double su2_cg(int j1,int j2,int j3,int m1,int m2){
  int m3 = m1 + m2;
  if (m3 < -j3 || m3 > j3) return 0.0;
  double p1 = (2.0*j3+1.0)*cfact(j1+j2-j3)*cfact(j1-j2+j3)*cfact(-j1+j2+j3)/cfact(j1+j2+j3+1);
  double p2 = cfact(j1+m1)*cfact(j1-m1)*cfact(j2+m2)*cfact(j2-m2)*cfact(j3+m3)*cfact(j3-m3);
  double pref = csqrt(p1*p2);
  int k0 = 0;
  if (j2-j3-m1 > k0) k0 = j2-j3-m1;
  if (j1+m2-j3 > k0) k0 = j1+m2-j3;
  int k1 = j1+j2-j3;
  if (j1-m1 < k1) k1 = j1-m1;
  if (j2+m2 < k1) k1 = j2+m2;
  double s = 0.0;
  for (int k = k0; k <= k1; ++k){
    double t = 1.0/(cfact(k)*cfact(j1+j2-j3-k)*cfact(j1-m1-k)*cfact(j2+m2-k)
                    *cfact(j3-j2+m1+k)*cfact(j3-j1-m2+k));
    s += (k & 1) ? -t : t;
  }
  return pref*s;
}

struct QRow { int n; int col[2]; CD q[2]; };
constexpr QRow qrow(int l, int r){
  QRow R{};
  constexpr double s2 = 0.70710678118654752440;
  int m = r - l;
  if (m < 0){
    R.n = 2;
    R.col[0] = l - m; R.q[0] = CD{s2, 0.0};
    R.col[1] = l + m; R.q[1] = CD{0.0, -s2};
  } else if (m == 0){
    R.n = 1; R.col[0] = l; R.q[0] = CD{1.0, 0.0};
  } else {
    double sg = (m & 1) ? -1.0 : 1.0;
    R.n = 2;
    R.col[0] = l + m; R.q[0] = CD{sg*s2, 0.0};
    R.col[1] = l - m; R.q[1] = CD{0.0, sg*s2};
  }
  int ph = l & 3;   // multiply by (-i)^l
  for (int t = 0; t < R.n; ++t){
    double a = R.q[t].re, b = R.q[t].im;
    if      (ph == 1) R.q[t] = CD{ b, -a};
    else if (ph == 2) R.q[t] = CD{-a, -b};
    else if (ph == 3) R.q[t] = CD{-b,  a};
  }
  return R;
}

constexpr int MAXNZ = 160;
struct W3NZ { int n; int ijk[MAXNZ]; float v[MAXNZ]; };

constexpr W3NZ build_w3(int l1,int l2,int l3){
  double re[7][7][7]{};
  int d1 = 2*l1+1, d2 = 2*l2+1, d3 = 2*l3+1;
  for (int i = 0; i < d1; ++i) for (int k = 0; k < d2; ++k){
    int m1 = i - l1, m2 = k - l2, m3 = m1 + m2;
    if (m3 < -l3 || m3 > l3) continue;
    int n = m3 + l3;
    double cg = su2_cg(l1,l2,l3,m1,m2);
    if (cg == 0.0) continue;
    QRow q1 = qrow(l1,i), q2 = qrow(l2,k), q3 = qrow(l3,n);
    for (int a = 0; a < q1.n; ++a) for (int b = 0; b < q2.n; ++b) for (int c = 0; c < q3.n; ++c){
      CD A = q1.q[a], B = q2.q[b], C = q3.q[c];
      C.im = -C.im;
      CD AB{A.re*B.re - A.im*B.im, A.re*B.im + A.im*B.re};
      double tre = AB.re*C.re - AB.im*C.im;
      re[q1.col[a]][q2.col[b]][q3.col[c]] += tre*cg;
    }
  }
  double nrm = 0.0;
  for (int i = 0; i < d1; ++i) for (int j = 0; j < d2; ++j) for (int k = 0; k < d3; ++k)
    nrm += re[i][j][k]*re[i][j][k];
  nrm = csqrt(nrm);
  W3NZ R{};
  for (int i = 0; i < d1; ++i) for (int j = 0; j < d2; ++j) for (int k = 0; k < d3; ++k){
    double val = re[i][j][k]/nrm;
    if (val > 1e-9 || val < -1e-9){
      R.ijk[R.n] = i | (j << 3) | (k << 6);
      R.v[R.n]   = (float)val;
      R.n++;
    }
  }
  return R;
}

struct C3 { int l1,l2,l3; };
constexpr C3 combo_at(int cid){
  int c = 0;
  for (int a = 0; a <= 3; ++a) for (int b = 0; b <= 3; ++b){
    int lmin = a > b ? a-b : b-a;
    int lmax = a+b > 3 ? 3 : a+b;
    for (int lo = lmin; lo <= lmax; ++lo){ if (c == cid) return C3{a,b,lo}; ++c; }
  }
  return C3{0,0,0};
}
constexpr int cid_of(int l1,int l2,int l3){
  int c = 0;
  for (int a = 0; a <= 3; ++a) for (int b = 0; b <= 3; ++b){
    int lmin = a > b ? a-b : b-a;
    int lmax = a+b > 3 ? 3 : a+b;
    for (int lo = lmin; lo <= lmax; ++lo){ if (a==l1 && b==l2 && lo==l3) return c; ++c; }
  }
  return -1;
}

template<int C> struct W3Tab {
  static constexpr W3NZ v = build_w3(combo_at(C).l1, combo_at(C).l2, combo_at(C).l3);
};

// ----------------------------------------------------------------------------
// Tensor-product path tables. scale folds sqrt((2lo+1)/fan) * 0.25 (neighbor
// normalization of the input node features).
// ----------------------------------------------------------------------------
struct Irr { int mul, l, p; };
constexpr Irr IRR_SH_A[4]  = {{1,0,1},{1,1,-1},{1,2,1},{1,3,-1}};
constexpr Irr IRR_MID_A[8] = {{5,0,-1},{5,0,1},{5,1,-1},{5,1,1},{5,2,-1},{5,2,1},{5,3,-1},{5,3,1}};
constexpr Irr IRR_OUT_A[1] = {{64,0,1}};

struct PathT { int o1,m1,l1,o2,l2,oo,mo,lo,ioi,wof,cid; float scale; };
struct TPD   { int np; int d1tot, d2tot, dotot, wtot; PathT p[68]; };

constexpr TPD build_tp(const Irr* I1, int n1, const Irr* I2, int n2, const Irr* IO, int no){
  TPD T{};
  int o1s[8]{}, o2s[8]{}, oos[8]{};
  { int off=0; for (int i=0;i<n1;++i){ o1s[i]=off; off += I1[i].mul*(2*I1[i].l+1); } T.d1tot=off; }
  { int off=0; for (int i=0;i<n2;++i){ o2s[i]=off; off += I2[i].mul*(2*I2[i].l+1); } T.d2tot=off; }
  { int off=0; for (int i=0;i<no;++i){ oos[i]=off; off += IO[i].mul*(2*IO[i].l+1); } T.dotot=off; }
  int wof = 0;
  for (int i1=0;i1<n1;++i1) for (int i2=0;i2<n2;++i2) for (int io=0;io<no;++io){
    int L1=I1[i1].l, L2=I2[i2].l, LO=IO[io].l;
    int dl = L1>L2 ? L1-L2 : L2-L1;
    if (IO[io].p == I1[i1].p*I2[i2].p && dl <= LO && LO <= L1+L2){
      PathT& P = T.p[T.np];
      P.o1=o1s[i1]; P.m1=I1[i1].mul; P.l1=L1;
      P.o2=o2s[i2]; P.l2=L2;
      P.oo=oos[io]; P.mo=IO[io].mul; P.lo=LO; P.ioi=io;
      P.wof=wof; P.cid=cid_of(L1,L2,LO);
      wof += I1[i1].mul * I2[i2].mul * IO[io].mul;
      T.np++;
    }
  }
  T.wtot = wof;
  for (int p = 0; p < T.np; ++p){
    int fan = 0;
    for (int q = 0; q < T.np; ++q) if (T.p[q].ioi == T.p[p].ioi) fan += T.p[q].m1;
    T.p[p].scale = (float)(csqrt((2.0*T.p[p].lo+1.0)/(double)fan) * 0.25);
  }
  return T;
}

template<int ID> struct TPSel;
template<> struct TPSel<0>{ static constexpr TPD v = build_tp(IRR_SH_A,4,  IRR_SH_A,4, IRR_MID_A,8); };
template<> struct TPSel<1>{ static constexpr TPD v = build_tp(IRR_MID_A,8, IRR_SH_A,4, IRR_MID_A,8); };
template<> struct TPSel<2>{ static constexpr TPD v = build_tp(IRR_MID_A,8, IRR_SH_A,4, IRR_OUT_A,1); };

static_assert(TPSel<0>::v.np == 34 && TPSel<0>::v.wtot == 170,  "TP_IN structure mismatch");
static_assert(TPSel<1>::v.np == 68 && TPSel<1>::v.wtot == 1700, "TP_LAYER structure mismatch");
static_assert(TPSel<2>::v.np == 4  && TPSel<2>::v.wtot == 1280, "TP_OUT structure mismatch");
static_assert(TPSel<0>::v.d1tot == 16 && TPSel<0>::v.dotot == 160, "dims");
static_assert(TPSel<1>::v.d1tot == 160 && TPSel<1>::v.dotot == 160, "dims");
static_assert(TPSel<2>::v.d1tot == 160 && TPSel<2>::v.dotot == 64, "dims");

constexpr int out_off_of(const TPD& T, int io){
  for (int q = 0; q < T.np; ++q) if (T.p[q].ioi == io) return T.p[q].oo; return 0;
}
constexpr int acc_of_io(int IO){ return 5*(2*IRR_MID_A[IO].l + 1); }
constexpr int colbase(int MASK, int IO){
  int c = 0; for (int i = 0; i < IO; ++i) if ((MASK>>i)&1) c += acc_of_io(i); return c;
}
constexpr int pass_cols(int MASK){
  int c = 0; for (int i = 0; i < 8; ++i) if ((MASK>>i)&1) c += acc_of_io(i); return c;
}
// 4 balanced 40-col passes: {l0,l3} odd, {l1,l2} odd, {l0,l3} even, {l1,l2} even
constexpr int PASS_MASKS[4] = {0x41, 0x14, 0x82, 0x28};
static_assert(pass_cols(0x41)==40 && pass_cols(0x14)==40 &&
              pass_cols(0x82)==40 && pass_cols(0x28)==40, "pass split");

// Compile-time for-loop
template<int V> struct IC { static constexpr int value = V; };
template<int I, int N, class F>
__device__ __forceinline__ void sfor(F&& f){
  if constexpr (N - I == 1){ f(IC<I>{}); }
  else if constexpr (N - I > 1){
    constexpr int M = I + (N - I)/2;
    sfor<I, M>(f);
    sfor<M, N>(f);
  }
}

// ============================================================================
// Kernels
// ============================================================================

__device__ __forceinline__ void sh16(float x, float y, float z, float* b){
  const float s3 = 1.7320508075688772f, s5 = 2.2360679774997896f, s7 = 2.6457513110645907f;
  const float c30 = 0.9128709291752769f;   // sqrt(5/6)
  const float c32 = 0.6123724356957945f;   // sqrt(3/8)
  float y2 = y*y, x2z2 = x*x + z*z;
  float sh20 = s3*x*z, sh21 = s3*x*y, sh22 = y2 - 0.5f*x2z2, sh23 = s3*y*z, sh24 = 0.5f*s3*(z*z - x*x);
  float sh30 = c30*(sh20*z + sh24*x);
  float sh31 = s5*sh20*y;
  float sh32 = c32*(4.0f*y2 - x2z2)*x;
  float sh33 = 0.5f*y*(2.0f*y2 - 3.0f*x2z2);
  float sh34 = c32*z*(4.0f*y2 - x2z2);
  float sh35 = s5*sh24*y;
  float sh36 = c30*(sh24*z - sh20*x);
  b[0]=1.0f; b[1]=s3*x; b[2]=s3*y; b[3]=s3*z;
  b[4]=s5*sh20; b[5]=s5*sh21; b[6]=s5*sh22; b[7]=s5*sh23; b[8]=s5*sh24;
  b[9]=s7*sh30; b[10]=s7*sh31; b[11]=s7*sh32; b[12]=s7*sh33; b[13]=s7*sh34; b[14]=s7*sh35; b[15]=s7*sh36;
}

__device__ __forceinline__ void load16(const float* __restrict__ p, float* b){
  const float4* sp = (const float4*)p;
  float4 q0=sp[0], q1=sp[1], q2=sp[2], q3=sp[3];
  b[0]=q0.x; b[1]=q0.y; b[2]=q0.z;  b[3]=q0.w;
  b[4]=q1.x; b[5]=q1.y; b[6]=q1.z;  b[7]=q1.w;
  b[8]=q2.x; b[9]=q2.y; b[10]=q2.z; b[11]=q2.w;
  b[12]=q3.x;b[13]=q3.y;b[14]=q3.z; b[15]=q3.w;
}

// --- CSR build --------------------------------------------------------------

__global__ void __launch_bounds__(256) k_hist(const int* __restrict__ dst,
    int* __restrict__ deg, int E){
  int e = blockIdx.x*256 + threadIdx.x;
  if (e < E) atomicAdd(&deg[dst[e]], 1);
}

__global__ void __launch_bounds__(256) k_scan(const int* __restrict__ deg,
    int* __restrict__ row_start, int* __restrict__ cursor, int N){
  __shared__ int part[256];
  int t = threadIdx.x;
  int M = N + 1;
  int CH = (M + 255) / 256;
  int base = t * CH;
  int s = 0;
  for (int k = 0; k < CH; ++k){
    int idx = base + k;
    if (idx < N) s += deg[idx];
  }
  part[t] = s;
  __syncthreads();
  if (t == 0){
    int run = 0;
    for (int i = 0; i < 256; ++i){ int v = part[i]; part[i] = run; run += v; }
  }
  __syncthreads();
  int run = part[t];
  for (int k = 0; k < CH; ++k){
    int idx = base + k;
    if (idx < M){
      row_start[idx] = run;
      cursor[idx] = run;
      if (idx < N) run += deg[idx];
    }
  }
}

__global__ void __launch_bounds__(256) k_fill(const int* __restrict__ src,
    const int* __restrict__ dst, const float* __restrict__ evec,
    int* __restrict__ cursor, int* __restrict__ csr_src, float* __restrict__ csr_sh, int E){
  int e = blockIdx.x*256 + threadIdx.x;
  if (e >= E) return;
  int d = dst[e];
  int pos = atomicAdd(&cursor[d], 1);
  csr_src[pos] = src[e];
  float b[16];
  sh16(evec[3*(size_t)e], evec[3*(size_t)e+1], evec[3*(size_t)e+2], b);
  float4* o = (float4*)(csr_sh + (size_t)pos*16);
  o[0] = make_float4(b[0],b[1],b[2],b[3]);
  o[1] = make_float4(b[4],b[5],b[6],b[7]);
  o[2] = make_float4(b[8],b[9],b[10],b[11]);
  o[3] = make_float4(b[12],b[13],b[14],b[15]);
}

// nodeA[n][d] = sum of csr_sh rows of node n (raw, un-normalized)
__global__ void __launch_bounds__(256) k_nodeA(const float* __restrict__ csr_sh,
    const int* __restrict__ row_start, float* __restrict__ nodeA, int N){
  int gid = blockIdx.x*256 + threadIdx.x;
  if (gid >= N*16) return;
  int n = gid >> 4, d = gid & 15;
  int rs = row_start[n], re = row_start[n+1];
  float s = 0.f;
  for (int j = rs; j < re; ++j) s += csr_sh[(size_t)j*16 + d];
  nodeA[gid] = s;
}

// --- edge-parallel TP: one thread per CSR edge, column-major ef output ------
// MASK selects which output irreps (of the 8 IRR_MID blocks) this pass emits;
// per-IO accumulators are stored immediately to keep VGPRs low.

template<int TPID, int MASK>
__global__ void __launch_bounds__(256) k_tp_edge(
    const float* __restrict__ nin, const float* __restrict__ csr_sh,
    const int* __restrict__ csr_src, const float* __restrict__ w,
    float* __restrict__ ef, int E)
{
  constexpr int D1 = TPSel<TPID>::v.d1tot;
  int j = blockIdx.x*256 + (int)threadIdx.x;
  if (j >= E) return;
  float b[16];
  load16(csr_sh + (size_t)j*16, b);
  const float* __restrict__ arow = nin + (size_t)csr_src[j]*D1;
  float a16[16];
  if constexpr (TPID == 0) load16(arow, a16);

  sfor<0, 8>([&](auto IOC){
    constexpr int IO = decltype(IOC)::value;
    if constexpr ((MASK >> IO) & 1){
      constexpr Irr OI = IRR_MID_A[IO];
      constexpr int dd  = 2*OI.l + 1;
      constexpr int ACC = 5*dd;
      float acc[ACC];
      #pragma unroll
      for (int i = 0; i < ACC; ++i) acc[i] = 0.0f;

      sfor<0, TPSel<TPID>::v.np>([&](auto PC){
        constexpr PathT P = TPSel<TPID>::v.p[decltype(PC)::value];
        if constexpr (P.ioi == IO){
          constexpr int d1 = 2*P.l1 + 1;
          float av[P.m1*d1];
          #pragma unroll
          for (int i = 0; i < P.m1*d1; ++i){
            if constexpr (TPID == 0) av[i] = a16[P.o1 + i];
            else                     av[i] = arow[P.o1 + i];
          }
          float t[P.m1*dd];
          #pragma unroll
          for (int i = 0; i < P.m1*dd; ++i) t[i] = 0.0f;
          sfor<0, W3Tab<P.cid>::v.n>([&](auto NI){
            constexpr int ni  = decltype(NI)::value;
            constexpr int ijk = W3Tab<P.cid>::v.ijk[ni];
            constexpr int ii = ijk & 7, jj = (ijk >> 3) & 7, kk = ijk >> 6;
            constexpr float v = W3Tab<P.cid>::v.v[ni];
            float bv = b[P.o2 + jj] * v;
            #pragma unroll
            for (int u = 0; u < P.m1; ++u) t[u*dd + kk] += av[u*d1 + ii]*bv;
          });
          #pragma unroll
          for (int u = 0; u < P.m1; ++u){
            #pragma unroll
            for (int wj = 0; wj < 5; ++wj){
              float wv = w[P.wof + u*5 + wj] * P.scale;   // wave-uniform -> s_load
              #pragma unroll
              for (int k = 0; k < dd; ++k) acc[wj*dd + k] += wv * t[u*dd + k];
            }
          }
        }
      });

      constexpr int CB = colbase(MASK, IO);
      #pragma unroll
      for (int i = 0; i < ACC; ++i) ef[(size_t)(CB + i)*E + j] = acc[i];
    }
  });
}

// TP_OUT edge stage: only the 20 CG scalars t[path][u]*scale (weight mixing
// is linear -> deferred past both segment sums to k_final).
__global__ void __launch_bounds__(256) k_tp2_edge(
    const float* __restrict__ nin, const float* __restrict__ csr_sh,
    const int* __restrict__ csr_src, float* __restrict__ ef, int E)
{
  int j = blockIdx.x*256 + (int)threadIdx.x;
  if (j >= E) return;
  float b[16];
  load16(csr_sh + (size_t)j*16, b);
  const float* __restrict__ arow = nin + (size_t)csr_src[j]*160;
  sfor<0, 4>([&](auto PC){
    constexpr int pi = decltype(PC)::value;
    constexpr PathT P = TPSel<2>::v.p[pi];
    constexpr int d1 = 2*P.l1 + 1;
    float t[5];
    #pragma unroll
    for (int u = 0; u < 5; ++u) t[u] = 0.0f;
    sfor<0, W3Tab<P.cid>::v.n>([&](auto NI){
      constexpr int ni  = decltype(NI)::value;
      constexpr int ijk = W3Tab<P.cid>::v.ijk[ni];
      constexpr int ii = ijk & 7, jj = (ijk >> 3) & 7;
      constexpr float v = W3Tab<P.cid>::v.v[ni];
      float bv = b[P.o2 + jj] * v;
      #pragma unroll
      for (int u = 0; u < 5; ++u) t[u] += arow[P.o1 + u*d1 + ii]*bv;
    });
    #pragma unroll
    for (int u = 0; u < 5; ++u) ef[(size_t)(pi*5 + u)*E + j] = t[u]*P.scale;
  });
}

// --- segment reduce: contiguous CSR ranges, no atomics ----------------------
template<int MASK>
__global__ void __launch_bounds__(256) k_red(const float* __restrict__ ef,
    const int* __restrict__ row_start, float* __restrict__ nout, int N, int E)
{
  int n = blockIdx.x*256 + (int)threadIdx.x;
  if (n >= N) return;
  int d = blockIdx.y;
  int rs = row_start[n], re = row_start[n+1];
  const float* __restrict__ col = ef + (size_t)d*E;
  float s = 0.f;
  for (int j = rs; j < re; ++j) s += col[j];
  int oc = 0;
  sfor<0, 8>([&](auto IOC){
    constexpr int IO = decltype(IOC)::value;
    if constexpr ((MASK >> IO) & 1){
      constexpr int CB  = colbase(MASK, IO);
      constexpr int ACC = acc_of_io(IO);
      constexpr int OB  = out_off_of(TPSel<1>::v, IO);   // same layout for TP0/TP1
      if (d >= CB && d < CB + ACC) oc = OB + (d - CB);
    }
  });
  nout[(size_t)n*160 + oc] = s;
}

// TP_OUT reduce: 20 identity columns into nodeT[N][20]
__global__ void __launch_bounds__(256) k_redT(const float* __restrict__ ef,
    const int* __restrict__ row_start, float* __restrict__ nodeT, int N, int E)
{
  int n = blockIdx.x*256 + (int)threadIdx.x;
  if (n >= N) return;
  int d = blockIdx.y;
  int rs = row_start[n], re = row_start[n+1];
  const float* __restrict__ col = ef + (size_t)d*E;
  float s = 0.f;
  for (int j = rs; j < re; ++j) s += col[j];
  nodeT[(size_t)n*20 + d] = s;
}

// --- final: per-graph sum of nodeT, then TP_OUT weight mixing ---------------
__device__ __forceinline__ int lbound(const int* __restrict__ a, int n, int key){
  int lo = 0, hi = n;
  while (lo < hi){ int m = (lo + hi) >> 1; if (a[m] < key) lo = m + 1; else hi = m; }
  return lo;
}

__global__ void __launch_bounds__(64) k_final(const float* __restrict__ nodeT,
    const int* __restrict__ batch, const float* __restrict__ w,
    float* __restrict__ out, int N){
  int g = blockIdx.x, f = threadIdx.x;
  int lo = lbound(batch, N, g), hi = lbound(batch, N, g + 1);
  __shared__ float gt[20];
  if (f < 20){
    float s = 0.f;
    for (int n = lo; n < hi; ++n) s += nodeT[(size_t)n*20 + f];
    gt[f] = s;
  }
  __syncthreads();
  float o = 0.f;
  sfor<0, 4>([&](auto PC){
    constexpr int pi = decltype(PC)::value;
    constexpr PathT P = TPSel<2>::v.p[pi];
    #pragma unroll
    for (int u = 0; u < 5; ++u) o += w[P.wof + u*64 + f] * gt[pi*5 + u];
  });
  out[(size_t)g*64 + f] = o * 2.5e-6f;   // 0.25 (TP2-out inv) / sqrt(100) / 1e4
}

// ============================================================================
extern "C" void kernel_launch(void* const* d_in, const int* in_sizes, int n_in,
                              void* d_out, int out_size, void* d_ws, size_t ws_size,
                              hipStream_t stream){
  const int*   eidx  = (const int*)d_in[0];
  const float* evec  = (const float*)d_in[1];
  const int*   batch = (const int*)d_in[2];
  const float* w_in  = (const float*)d_in[3];
  const float* w_ly  = (const float*)d_in[4];
  const float* w_out = (const float*)d_in[5];

  const int E = in_sizes[0]/2;   // 400000
  const int N = in_sizes[2];     // 25000
  const int G = out_size/64;     // 250
  const int* src = eidx;
  const int* dstp = eidx + E;

  const int NP = (N + 1 + 3) & ~3;
  int*   deg       = (int*)d_ws;             // [NP]
  int*   row_start = deg + NP;               // [NP]
  int*   cursor    = row_start + NP;         // [NP]
  int*   csr_src   = cursor + NP;            // [E]
  float* csr_sh    = (float*)(csr_src + E);  // [E,16] row-major
  float* nodeA     = csr_sh + (size_t)E*16;  // [N,16]
  float* nodeB     = nodeA + (size_t)N*16;   // [N,160]
  float* nodeC     = nodeB + (size_t)N*160;  // [N,160]
  float* nodeT     = nodeC + (size_t)N*160;  // [N,20]
  float* ef        = nodeT + (size_t)N*20;   // [40,E] column-major (64 MB)

  hipMemsetAsync(deg, 0, (size_t)NP*sizeof(int), stream);

  int nbE = (E + 255)/256;
  int nbN256 = (N + 255)/256;
  k_hist<<<nbE, 256, 0, stream>>>(dstp, deg, E);
  k_scan<<<1, 256, 0, stream>>>(deg, row_start, cursor, N);
  k_fill<<<nbE, 256, 0, stream>>>(src, dstp, evec, cursor, csr_src, csr_sh, E);
  k_nodeA<<<(N*16 + 255)/256, 256, 0, stream>>>(csr_sh, row_start, nodeA, N);

  dim3 rgrid(nbN256, 40, 1);

  // TP0: nodeA -> nodeB (4 passes x 40 cols)
  k_tp_edge<0,0x41><<<nbE, 256, 0, stream>>>(nodeA, csr_sh, csr_src, w_in, ef, E);
  k_red<0x41><<<rgrid, 256, 0, stream>>>(ef, row_start, nodeB, N, E);
  k_tp_edge<0,0x14><<<nbE, 256, 0, stream>>>(nodeA, csr_sh, csr_src, w_in, ef, E);
  k_red<0x14><<<rgrid, 256, 0, stream>>>(ef, row_start, nodeB, N, E);
  k_tp_edge<0,0x82><<<nbE, 256, 0, stream>>>(nodeA, csr_sh, csr_src, w_in, ef, E);
  k_red<0x82><<<rgrid, 256, 0, stream>>>(ef, row_start, nodeB, N, E);
  k_tp_edge<0,0x28><<<nbE, 256, 0, stream>>>(nodeA, csr_sh, csr_src, w_in, ef, E);
  k_red<0x28><<<rgrid, 256, 0, stream>>>(ef, row_start, nodeB, N, E);

  // TP1: nodeB -> nodeC
  k_tp_edge<1,0x41><<<nbE, 256, 0, stream>>>(nodeB, csr_sh, csr_src, w_ly, ef, E);
  k_red<0x41><<<rgrid, 256, 0, stream>>>(ef, row_start, nodeC, N, E);
  k_tp_edge<1,0x14><<<nbE, 256, 0, stream>>>(nodeB, csr_sh, csr_src, w_ly, ef, E);
  k_red<0x14><<<rgrid, 256, 0, stream>>>(ef, row_start, nodeC, N, E);
  k_tp_edge<1,0x82><<<nbE, 256, 0, stream>>>(nodeB, csr_sh, csr_src, w_ly, ef, E);
  k_red<0x82><<<rgrid, 256, 0, stream>>>(ef, row_start, nodeC, N, E);
  k_tp_edge<1,0x28><<<nbE, 256, 0, stream>>>(nodeB, csr_sh, csr_src, w_ly, ef, E);
  k_red<0x28><<<rgrid, 256, 0, stream>>>(ef, row_start, nodeC, N, E);

  // TP2: nodeC -> nodeT (CG only; weights deferred to k_final)
  k_tp2_edge<<<nbE, 256, 0, stream>>>(nodeC, csr_sh, csr_src, ef, E);
  dim3 tgrid(nbN256, 20, 1);
  k_redT<<<tgrid, 256, 0, stream>>>(ef, row_start, nodeT, N, E);

  k_final<<<G, 64, 0, stream>>>(nodeT, batch, w_out, (float*)d_out, N);
}